// Round 1
// baseline (282.874 us; speedup 1.0000x reference)
//
#include <hip/hip_runtime.h>

#define GRP   8
#define PCH   64     // in-channels per group
#define FO    256    // out filters
#define CIN   512
#define PTILE 16     // positions per block

__device__ __forceinline__ unsigned short f2bf(float f) {
    unsigned u = __float_as_uint(f);
    u = u + 0x7FFFu + ((u >> 16) & 1u);   // RNE to bf16
    return (unsigned short)(u >> 16);
}
__device__ __forceinline__ float bf2f(unsigned short h) {
    return __uint_as_float(((unsigned)h) << 16);
}
__device__ __forceinline__ float sigmoidf(float b) {
    return 1.0f / (1.0f + __expf(-b));
}
// upper-triangular index for (i,j), i<=j, in 8x8
__device__ __forceinline__ constexpr int TRI(int i, int j) {
    int a = i < j ? i : j, b = i < j ? j : i;
    return a * 8 - a * (a - 1) / 2 + (b - a);
}

__global__ __launch_bounds__(256, 2)
void dynroute_fp32(const float* __restrict__ x, const float* __restrict__ wk,
                   const float* __restrict__ bias, float* __restrict__ out) {
    __shared__ unsigned short con_s[PTILE][GRP][FO];  // 64 KB, bf16 con
    __shared__ float xs[PTILE][PCH];                  // 4 KB
    __shared__ float alpha_s[PTILE][GRP];             // 512 B

    const int tid = threadIdx.x;
    const int f = tid;                                // output filter 0..255
    const long m0 = (long)blockIdx.x * PTILE;

    // ---------------- Phase 1: grouped GEMM, con -> LDS (bf16) -------------
    for (int g = 0; g < GRP; ++g) {
        // W column for this (g, f): each W element read exactly once per block
        float w[PCH];
        const float* wg = wk + (size_t)g * PCH * FO + f;
        #pragma unroll
        for (int p = 0; p < PCH; ++p) w[p] = wg[(size_t)p * FO];

        __syncthreads();  // previous iteration done reading xs
        {   // stage x[:, g*64 .. g*64+64) for PTILE positions (coalesced)
            const int pos = tid >> 4;       // 0..15
            const int c4  = tid & 15;       // 0..15
            const float4 v = *reinterpret_cast<const float4*>(
                x + (m0 + pos) * CIN + g * PCH + c4 * 4);
            *reinterpret_cast<float4*>(&xs[pos][c4 * 4]) = v;
        }
        __syncthreads();

        #pragma unroll 2
        for (int pos = 0; pos < PTILE; ++pos) {
            float a0 = 0.f, a1 = 0.f, a2 = 0.f, a3 = 0.f;
            #pragma unroll
            for (int q = 0; q < PCH / 4; ++q) {
                const float4 xv = *reinterpret_cast<const float4*>(&xs[pos][q * 4]);
                a0 = fmaf(xv.x, w[q * 4 + 0], a0);
                a1 = fmaf(xv.y, w[q * 4 + 1], a1);
                a2 = fmaf(xv.z, w[q * 4 + 2], a2);
                a3 = fmaf(xv.w, w[q * 4 + 3], a3);
            }
            con_s[pos][g][f] = f2bf((a0 + a1) + (a2 + a3));
        }
    }
    __syncthreads();

    // ---------------- Phase 2: per-position Gram + routing -----------------
    {
        const int t = tid & 31;  // 32 threads per position
        #pragma unroll
        for (int rnd = 0; rnd < PTILE / 8; ++rnd) {
            const int pos = rnd * 8 + (tid >> 5);
            // this thread's 8 f-values: {4t..4t+3} and {128+4t..128+4t+3}
            float c[GRP][8];
            #pragma unroll
            for (int g = 0; g < GRP; ++g) {
                const uint2 v0 = *reinterpret_cast<const uint2*>(&con_s[pos][g][4 * t]);
                const uint2 v1 = *reinterpret_cast<const uint2*>(&con_s[pos][g][128 + 4 * t]);
                c[g][0] = bf2f((unsigned short)(v0.x & 0xffffu));
                c[g][1] = bf2f((unsigned short)(v0.x >> 16));
                c[g][2] = bf2f((unsigned short)(v0.y & 0xffffu));
                c[g][3] = bf2f((unsigned short)(v0.y >> 16));
                c[g][4] = bf2f((unsigned short)(v1.x & 0xffffu));
                c[g][5] = bf2f((unsigned short)(v1.x >> 16));
                c[g][6] = bf2f((unsigned short)(v1.y & 0xffffu));
                c[g][7] = bf2f((unsigned short)(v1.y >> 16));
            }
            // 36 unique pair partial dot-products over local 8 f
            float pg[36];
            {
                int idx = 0;
                #pragma unroll
                for (int gi = 0; gi < GRP; ++gi)
                    #pragma unroll
                    for (int gj = gi; gj < GRP; ++gj) {
                        float s = 0.f;
                        #pragma unroll
                        for (int k = 0; k < 8; ++k) s = fmaf(c[gi][k], c[gj][k], s);
                        pg[idx++] = s;
                    }
            }
            // butterfly reduce over the 32 threads of this position
            #pragma unroll
            for (int i = 0; i < 36; ++i) {
                #pragma unroll
                for (int m = 1; m <= 16; m <<= 1)
                    pg[i] += __shfl_xor(pg[i], m, 64);
            }
            if (t == 0) {
                // serial dynamic routing on the 8x8 Gram
                float b1[GRP], a1v[GRP];
                #pragma unroll
                for (int gi = 0; gi < GRP; ++gi) {
                    float s = 0.f;
                    #pragma unroll
                    for (int gj = 0; gj < GRP; ++gj) s += pg[TRI(gi, gj)];
                    b1[gi] = 0.5f * s;
                    a1v[gi] = sigmoidf(b1[gi]);
                }
                #pragma unroll
                for (int gi = 0; gi < GRP; ++gi) {
                    float s = b1[gi];
                    #pragma unroll
                    for (int gj = 0; gj < GRP; ++gj) s = fmaf(pg[TRI(gi, gj)], a1v[gj], s);
                    alpha_s[pos][gi] = sigmoidf(s);
                }
            }
        }
    }
    __syncthreads();

    // ---------------- Phase 3: out = con^T * alpha2 + bias -----------------
    {
        const float bf = bias[f];
        #pragma unroll 2
        for (int pos = 0; pos < PTILE; ++pos) {
            float s = bf;
            #pragma unroll
            for (int g = 0; g < GRP; ++g)
                s = fmaf(alpha_s[pos][g], bf2f(con_s[pos][g][f]), s);
            out[(m0 + pos) * FO + f] = s;
        }
    }
}

extern "C" void kernel_launch(void* const* d_in, const int* in_sizes, int n_in,
                              void* d_out, int out_size, void* d_ws, size_t ws_size,
                              hipStream_t stream) {
    const float* x    = (const float*)d_in[0];
    const float* wk   = (const float*)d_in[1];
    const float* bias = (const float*)d_in[2];
    float* out        = (float*)d_out;
    const int M = in_sizes[0] / CIN;          // 25088, divisible by PTILE
    dim3 grid(M / PTILE), block(256);
    hipLaunchKernelGGL(dynroute_fp32, grid, block, 0, stream, x, wk, bias, out);
}

// Round 2
// 69.369 us; speedup vs baseline: 4.0778x; 4.0778x over previous
//
#include <hip/hip_runtime.h>

#define GRP   8
#define PCH   64
#define FO    256
#define CIN   512
#define PTILE 16
#define GSTR  264                  // u16 stride between g-rows in con_s (528 B, 16B-aligned, bank-spread)
#define PSTR  (8 * GSTR + 16)      // 2128 u16 stride between positions (4256 B)
#define CON_ELEMS (PTILE * PSTR + 8 * GSTR + 64)   // slack: gram phase reads junk gidx 8..15

typedef __attribute__((ext_vector_type(8))) short bf16x8;
typedef __attribute__((ext_vector_type(4))) float f32x4;

__device__ __forceinline__ unsigned f2bf(float f) {
    unsigned u = __float_as_uint(f);
    u = u + 0x7FFFu + ((u >> 16) & 1u);   // RNE
    return u >> 16;
}
__device__ __forceinline__ float bf2f(unsigned short h) {
    return __uint_as_float(((unsigned)h) << 16);
}
__device__ __forceinline__ float sigmoidf_(float b) {
    return 1.0f / (1.0f + __expf(-b));
}

// ---- pre-kernel: repack kernels fp32 [g][p][f] -> bf16 MFMA A-frag order ----
// layout: wpk[g][t][kb][lane][j], element = w[g][ p=kb*32+(lane>>4)*8+j ][ f=t*16+(lane&15) ]
__global__ void repack_w(const float* __restrict__ wk, unsigned short* __restrict__ wpk) {
    int id = blockIdx.x * 256 + threadIdx.x;      // 0 .. 131071
    int j    = id & 7;
    int lane = (id >> 3) & 63;
    int kb   = (id >> 9) & 1;
    int t    = (id >> 10) & 15;
    int g    = id >> 14;
    int p = kb * 32 + (lane >> 4) * 8 + j;
    int f = t * 16 + (lane & 15);
    wpk[id] = (unsigned short)f2bf(wk[(g * PCH + p) * FO + f]);
}

__global__ __launch_bounds__(256, 2)
void dynroute_mfma(const float* __restrict__ x, const unsigned short* __restrict__ wpk,
                   const float* __restrict__ bias, float* __restrict__ out) {
    __shared__ unsigned short con_s[CON_ELEMS];    // ~72.5 KB
    __shared__ float alpha_s[PTILE][GRP];

    const int tid  = threadIdx.x;
    const int lane = tid & 63;
    const int wave = tid >> 6;
    const int pos  = lane & 15;
    const int lq   = lane >> 4;
    const long m0  = (long)blockIdx.x * PTILE;

    // ---------------- Phase 1: grouped GEMM via MFMA, con -> LDS (bf16) ----
    // D[f_local][pos]: A = w-frag (m=f_local=lane&15 at pack time), B = x-frag (n=pos=lane&15)
    const float* xb = x + (m0 + pos) * CIN + lq * 8;
    for (int g = 0; g < GRP; ++g) {
        const float4 a0 = *reinterpret_cast<const float4*>(xb + g * PCH);
        const float4 a1 = *reinterpret_cast<const float4*>(xb + g * PCH + 4);
        const float4 b0 = *reinterpret_cast<const float4*>(xb + g * PCH + 32);
        const float4 b1 = *reinterpret_cast<const float4*>(xb + g * PCH + 36);
        bf16x8 xf0, xf1;
        xf0[0] = (short)f2bf(a0.x); xf0[1] = (short)f2bf(a0.y);
        xf0[2] = (short)f2bf(a0.z); xf0[3] = (short)f2bf(a0.w);
        xf0[4] = (short)f2bf(a1.x); xf0[5] = (short)f2bf(a1.y);
        xf0[6] = (short)f2bf(a1.z); xf0[7] = (short)f2bf(a1.w);
        xf1[0] = (short)f2bf(b0.x); xf1[1] = (short)f2bf(b0.y);
        xf1[2] = (short)f2bf(b0.z); xf1[3] = (short)f2bf(b0.w);
        xf1[4] = (short)f2bf(b1.x); xf1[5] = (short)f2bf(b1.y);
        xf1[6] = (short)f2bf(b1.z); xf1[7] = (short)f2bf(b1.w);

        #pragma unroll
        for (int tt = 0; tt < 4; ++tt) {
            const int t = wave * 4 + tt;
            const bf16x8 wf0 = *reinterpret_cast<const bf16x8*>(
                wpk + ((((g * 16 + t) * 2 + 0) * 64 + lane) << 3));
            const bf16x8 wf1 = *reinterpret_cast<const bf16x8*>(
                wpk + ((((g * 16 + t) * 2 + 1) * 64 + lane) << 3));
            f32x4 acc = {0.f, 0.f, 0.f, 0.f};
            acc = __builtin_amdgcn_mfma_f32_16x16x32_bf16(wf0, xf0, acc, 0, 0, 0);
            acc = __builtin_amdgcn_mfma_f32_16x16x32_bf16(wf1, xf1, acc, 0, 0, 0);
            // lane holds con[pos][f = t*16 + lq*4 + r], r=0..3 -> one b64 write
            unsigned lo = f2bf(acc[0]) | (f2bf(acc[1]) << 16);
            unsigned hi = f2bf(acc[2]) | (f2bf(acc[3]) << 16);
            uint2 v; v.x = lo; v.y = hi;
            *reinterpret_cast<uint2*>(&con_s[pos * PSTR + g * GSTR + t * 16 + lq * 4]) = v;
        }
    }
    __syncthreads();

    // ---------------- Phase 2: Gram via MFMA (A == B frag) + routing -------
    // frag: lane holds con[g = lane&15][f = ch*32 + lq*8 + j]; D = con * con^T
    for (int pp = 0; pp < 4; ++pp) {
        const int p2 = wave * 4 + pp;
        const int gidx = lane & 15;
        f32x4 gacc = {0.f, 0.f, 0.f, 0.f};
        #pragma unroll
        for (int ch = 0; ch < 8; ++ch) {
            const bf16x8 cf = *reinterpret_cast<const bf16x8*>(
                &con_s[p2 * PSTR + gidx * GSTR + ch * 32 + lq * 8]);
            gacc = __builtin_amdgcn_mfma_f32_16x16x32_bf16(cf, cf, gacc, 0, 0, 0);
        }
        // lane holds G[row = lq*4 + r][col = gidx]; rows/cols >= 8 are junk -> zero cols
        float gr[4];
        #pragma unroll
        for (int r = 0; r < 4; ++r) gr[r] = (gidx < 8) ? gacc[r] : 0.f;
        // row sums over 8 columns (butterfly within 8-lane span)
        float b1[4], a1v[4];
        #pragma unroll
        for (int r = 0; r < 4; ++r) {
            float s = gr[r];
            s += __shfl_xor(s, 1, 64);
            s += __shfl_xor(s, 2, 64);
            s += __shfl_xor(s, 4, 64);
            b1[r] = 0.5f * s;
            a1v[r] = sigmoidf_(b1[r]);
        }
        // broadcast a1[0..7] to all lanes (rows 0-3 live in lanes 0.., rows 4-7 in lane 16..)
        float a1_all[8];
        #pragma unroll
        for (int cc = 0; cc < 8; ++cc)
            a1_all[cc] = __shfl(a1v[cc & 3], (cc >> 2) * 16, 64);
        // pick a1 for my column
        float a1c = 0.f;
        #pragma unroll
        for (int cc = 0; cc < 8; ++cc)
            a1c = (gidx == cc) ? a1_all[cc] : a1c;
        // beta2[r] = b1[r] + sum_c G[r][c] * a1[c];  alpha2 = sigmoid
        float a2[4];
        #pragma unroll
        for (int r = 0; r < 4; ++r) {
            float pt = gr[r] * a1c;
            pt += __shfl_xor(pt, 1, 64);
            pt += __shfl_xor(pt, 2, 64);
            pt += __shfl_xor(pt, 4, 64);
            a2[r] = sigmoidf_(b1[r] + pt);
        }
        if (gidx == 0 && lq < 2) {
            #pragma unroll
            for (int r = 0; r < 4; ++r)
                alpha_s[p2][lq * 4 + r] = a2[r];
        }
    }
    __syncthreads();

    // ---------------- Phase 3: out = con^T * alpha2 + bias -----------------
    {
        const int f = tid;
        const float bb = bias[f];
        #pragma unroll 2
        for (int p3 = 0; p3 < PTILE; ++p3) {
            float s = bb;
            #pragma unroll
            for (int g = 0; g < GRP; ++g)
                s = fmaf(alpha_s[p3][g], bf2f(con_s[p3 * PSTR + g * GSTR + f]), s);
            out[(m0 + p3) * FO + f] = s;
        }
    }
}

extern "C" void kernel_launch(void* const* d_in, const int* in_sizes, int n_in,
                              void* d_out, int out_size, void* d_ws, size_t ws_size,
                              hipStream_t stream) {
    const float* x    = (const float*)d_in[0];
    const float* wk   = (const float*)d_in[1];
    const float* bias = (const float*)d_in[2];
    float* out        = (float*)d_out;
    unsigned short* wpk = (unsigned short*)d_ws;   // 256 KB used

    hipLaunchKernelGGL(repack_w, dim3(512), dim3(256), 0, stream, wk, wpk);

    const int M = in_sizes[0] / CIN;               // 25088
    hipLaunchKernelGGL(dynroute_mfma, dim3(M / PTILE), dim3(256), 0, stream,
                       x, wpk, bias, out);
}